// Round 4
// baseline (104.799 us; speedup 1.0000x reference)
//
#include <hip/hip_runtime.h>
#include <hip/hip_bf16.h>
#include <stdint.h>

#define KP    416        // padded rank (396->416) and padded wemb (400->416)
#define RANKD 396
#define WEMB  400
#define TEMB  20
#define TAGS  25
#define BATCH 16
#define LSEQ  128
#define MROWS 126        // L-2
#define NM    2016       // 16*126
#define NMP   2048
#define ABC   15625
#define ABCP  15872      // 62*256
#define SCALE 0.050251890762960605f   // 1/sqrt(396)

typedef __attribute__((ext_vector_type(8))) short short8;
typedef __attribute__((ext_vector_type(4))) float f32x4;

// workspace layout (bytes)
#define OFF_T01  0                         // 2048*416*2      = 1,703,936
#define OFF_T02  1703936                   // 15872*416*2     = 13,205,504
#define OFF_WORD 14909440                  // 16*128*416*2    = 1,703,936
#define OFF_WT   16613376                  // 3*416*416*2     = 1,038,336
#define OFF_G    17651712                  // 3*25*416*4      = 124,800

#define GLOAD_LDS16(gp, lp) \
  __builtin_amdgcn_global_load_lds((const __attribute__((address_space(1))) uint32_t*)(gp), \
                                   (__attribute__((address_space(3))) uint32_t*)(lp), 16, 0, 0)

__device__ __forceinline__ uint16_t f2bf(float f) {
    union { float f; uint32_t u; } v; v.f = f;
    uint32_t u = v.u;
    return (uint16_t)((u + 0x7FFFu + ((u >> 16) & 1u)) >> 16);  // RNE
}

// ---- prep: word->bf16 pad | W->Wt bf16 pad | g4/g5/g6 fp32 (fused by block range)
#define J1_BLK 3328   // 16*128*416/256
#define J2_BLK 2028   // 3*416*416/256
#define J3_BLK 122    // ceil(3*25*416/256)
__global__ void k_prep(const float* __restrict__ word,
                       const float* __restrict__ W1, const float* __restrict__ W2,
                       const float* __restrict__ W3, const float* __restrict__ tag,
                       const float* __restrict__ T1, const float* __restrict__ T2,
                       const float* __restrict__ T3,
                       uint16_t* __restrict__ wordb, uint16_t* __restrict__ wt,
                       float* __restrict__ g) {
    int bx = blockIdx.x;
    if (bx < J1_BLK) {
        int idx = bx * 256 + threadIdx.x;
        int e = idx % KP, row = idx / KP;
        wordb[idx] = f2bf((e < WEMB) ? word[row * WEMB + e] : 0.f);
    } else if (bx < J1_BLK + J2_BLK) {
        int idx = (bx - J1_BLK) * 256 + threadIdx.x;
        int j = idx / (KP * KP);
        int rem = idx % (KP * KP);
        int k = rem / KP, e = rem % KP;
        const float* W = (j == 0) ? W1 : (j == 1) ? W2 : W3;
        wt[idx] = f2bf((k < RANKD && e < WEMB) ? W[e * RANKD + k] : 0.f);
    } else {
        int idx = (bx - J1_BLK - J2_BLK) * 256 + threadIdx.x;
        if (idx >= 3 * TAGS * KP) return;
        int j = idx / (TAGS * KP);
        int rem = idx % (TAGS * KP);
        int a = rem / KP, k = rem % KP;
        const float* T = (j == 0) ? T1 : (j == 1) ? T2 : T3;
        float s = 0.f;
        if (k < RANKD) {
            for (int e = 0; e < TEMB; ++e) s += tag[a * TEMB + e] * T[e * RANKD + k];
        }
        g[idx] = s;
    }
}

// ---- mid: t01 build (MFMA) blocks [0,896) | t02 build blocks [896,...)
#define T01_BLK 896    // 128 nm-tiles * 7 k-groups
#define T02_BLK 3224   // 15872*52/256
__global__ __launch_bounds__(256) void k_mid(const uint16_t* __restrict__ word,
                                             const uint16_t* __restrict__ wt,
                                             const float* __restrict__ g,
                                             uint16_t* __restrict__ t01,
                                             uint16_t* __restrict__ t02) {
    int bx = blockIdx.x;
    if (bx < T01_BLK) {
        int wid = threadIdx.x >> 6, lane = threadIdx.x & 63;
        int nmtile = bx & 127;
        int ktile = (bx >> 7) * 4 + wid;
        if (ktile >= KP / 16) return;
        int col_l = lane & 15, kblk = lane >> 4;
        int colk = ktile * 16 + col_l;
        f32x4 acc1 = {0.f, 0.f, 0.f, 0.f}, acc2 = acc1, acc3 = acc1;
        if (nmtile < NM / 16) {
            int nm_a = nmtile * 16 + col_l;
            int n = nm_a / MROWS, m = nm_a % MROWS;
            const uint16_t* arow = word + (size_t)(n * LSEQ + m) * KP;
            const uint16_t* b1 = wt + (size_t)colk * KP;
            const uint16_t* b2 = wt + (size_t)KP * KP + (size_t)colk * KP;
            const uint16_t* b3 = wt + (size_t)2 * KP * KP + (size_t)colk * KP;
            for (int e0 = 0; e0 < KP; e0 += 32) {
                int eo = e0 + kblk * 8;
                short8 a0 = *(const short8*)(arow + eo);
                short8 a1 = *(const short8*)(arow + KP + eo);
                short8 a2 = *(const short8*)(arow + 2 * KP + eo);
                short8 v1 = *(const short8*)(b1 + eo);
                short8 v2 = *(const short8*)(b2 + eo);
                short8 v3 = *(const short8*)(b3 + eo);
                acc1 = __builtin_amdgcn_mfma_f32_16x16x32_bf16(a0, v1, acc1, 0, 0, 0);
                acc2 = __builtin_amdgcn_mfma_f32_16x16x32_bf16(a1, v2, acc2, 0, 0, 0);
                acc3 = __builtin_amdgcn_mfma_f32_16x16x32_bf16(a2, v3, acc3, 0, 0, 0);
            }
        }
        for (int r = 0; r < 4; ++r) {
            int row = nmtile * 16 + kblk * 4 + r;
            float v = acc1[r] * acc2[r] * acc3[r] * SCALE;
            t01[(size_t)row * KP + colk] = f2bf(v);
        }
    } else {
        int idx = (bx - T01_BLK) * 256 + threadIdx.x;
        int abc = idx / (KP / 8), kc = idx % (KP / 8);
        int k0 = kc * 8;
        short8 o;
        if (abc < ABC) {
            int a = abc / 625, rem = abc % 625, b = rem / 25, c = rem % 25;
            const float4* ga = (const float4*)(g + (size_t)a * KP + k0);
            const float4* gb = (const float4*)(g + (size_t)TAGS * KP + (size_t)b * KP + k0);
            const float4* gc = (const float4*)(g + (size_t)2 * TAGS * KP + (size_t)c * KP + k0);
            float4 a0 = ga[0], a1 = ga[1];
            float4 b0 = gb[0], b1 = gb[1];
            float4 c0 = gc[0], c1 = gc[1];
            o[0] = (short)f2bf(a0.x * b0.x * c0.x);
            o[1] = (short)f2bf(a0.y * b0.y * c0.y);
            o[2] = (short)f2bf(a0.z * b0.z * c0.z);
            o[3] = (short)f2bf(a0.w * b0.w * c0.w);
            o[4] = (short)f2bf(a1.x * b1.x * c1.x);
            o[5] = (short)f2bf(a1.y * b1.y * c1.y);
            o[6] = (short)f2bf(a1.z * b1.z * c1.z);
            o[7] = (short)f2bf(a1.w * b1.w * c1.w);
        } else {
            for (int t = 0; t < 8; ++t) o[t] = 0;
        }
        *(short8*)(t02 + (size_t)abc * KP + k0) = o;
    }
}

// ---- final: score[2016][15625] = t01 @ t02^T
// 256x256 tile, BK=32, 8 waves (2Mx4N, wave-tile 128x64), depth-2 LDS dbuf,
// ONE __syncthreads per K-tile (stage-late into just-vacated buffer),
// 64 KB LDS -> 2 blocks/CU. LDS k-slot-major [ks][256][8] (0 bank conflicts).
__global__ __launch_bounds__(512, 2) void k_final(const uint16_t* __restrict__ t01,
                                                  const uint16_t* __restrict__ t02,
                                                  float* __restrict__ out) {
    __shared__ __align__(16) uint16_t ldsA[2][8192];   // 2 bufs x 16 KB
    __shared__ __align__(16) uint16_t ldsB[2][8192];
    const int tid = threadIdx.x;
    const int wid = tid >> 6, lane = tid & 63;
    const int col_l = lane & 15, kblk = lane >> 4;

    // XCD-aware bijective swizzle: 496 blocks = 8 XCD-chunks x 62
    const int bid = blockIdx.x;
    const int swz = (bid & 7) * 62 + (bid >> 3);
    const int mb = swz & 7, nb = swz >> 3;          // 8 M-blocks, 62 N-blocks
    const int brow = mb * 256, bcol = nb * 256;

    const int wrow = (wid >> 2) * 128, wcol = (wid & 3) * 64;

    // staging: per K-tile, tile 256x32 bf16 = 16KB = 2 chunks of 8KB.
    // thread -> (row = tid&255, ks-half = tid>>8); chunk1 = ks+2 (elems +16).
    const int rowS = tid & 255, ksS = tid >> 8;
    const uint16_t* gA0 = t01 + (size_t)(brow + rowS) * KP + ksS * 8;
    const uint16_t* gA1 = gA0 + 16;
    const uint16_t* gB0 = t02 + (size_t)(bcol + rowS) * KP + ksS * 8;
    const uint16_t* gB1 = gB0 + 16;
    const int c0 = wid * 512;            // wave-uniform LDS elem base, chunk 0
    const int c1 = 4096 + wid * 512;     // chunk 1

    f32x4 acc[8][4];
#pragma unroll
    for (int m = 0; m < 8; ++m)
#pragma unroll
        for (int n = 0; n < 4; ++n)
            acc[m][n] = (f32x4){0.f, 0.f, 0.f, 0.f};

    auto stage = [&](int buf, int kt) {
        GLOAD_LDS16(gA0 + kt * 32, &ldsA[buf][c0]);
        GLOAD_LDS16(gA1 + kt * 32, &ldsA[buf][c1]);
        GLOAD_LDS16(gB0 + kt * 32, &ldsB[buf][c0]);
        GLOAD_LDS16(gB1 + kt * 32, &ldsB[buf][c1]);
    };

    const int NT = KP / 32;   // 13
    stage(0, 0);
    stage(1, 1);
    __syncthreads();          // drains both prologue stages

    for (int kt = 0; kt < NT; ++kt) {
        const int cur = kt & 1;
        const uint16_t* bA = ldsA[cur];
        const uint16_t* bB = ldsB[cur];
        short8 aF[8], bF[4];
#pragma unroll
        for (int n = 0; n < 4; ++n)
            bF[n] = *(const short8*)(bB + kblk * 2048 + (wcol + n * 16 + col_l) * 8);
#pragma unroll
        for (int m = 0; m < 8; ++m)
            aF[m] = *(const short8*)(bA + kblk * 2048 + (wrow + m * 16 + col_l) * 8);
#pragma unroll
        for (int m = 0; m < 8; ++m)
#pragma unroll
            for (int n = 0; n < 4; ++n)
                acc[m][n] = __builtin_amdgcn_mfma_f32_16x16x32_bf16(aF[m], bF[n], acc[m][n], 0, 0, 0);
        if (kt + 1 < NT) {
            __syncthreads();                 // all waves done reading buf[cur];
                                             // also drains tile kt+1's loads (issued 1 iter ago)
            if (kt + 2 < NT) stage(cur, kt + 2);   // refill just-vacated buffer
        }
    }

    // epilogue: fp32 stores
#pragma unroll
    for (int m = 0; m < 8; ++m) {
        int row_b = brow + wrow + m * 16 + kblk * 4;
#pragma unroll
        for (int n = 0; n < 4; ++n) {
            int col = bcol + wcol + n * 16 + col_l;
            if (col < ABC) {
#pragma unroll
                for (int r = 0; r < 4; ++r) {
                    int row = row_b + r;
                    if (row < NM) out[(size_t)row * ABC + col] = acc[m][n][r];
                }
            }
        }
    }
}

extern "C" void kernel_launch(void* const* d_in, const int* in_sizes, int n_in,
                              void* d_out, int out_size, void* d_ws, size_t ws_size,
                              hipStream_t stream) {
    const float* word = (const float*)d_in[0];
    const float* tag  = (const float*)d_in[1];
    const float* W1   = (const float*)d_in[2];
    const float* W2   = (const float*)d_in[3];
    const float* W3   = (const float*)d_in[4];
    const float* T1   = (const float*)d_in[5];
    const float* T2   = (const float*)d_in[6];
    const float* T3   = (const float*)d_in[7];
    float* out = (float*)d_out;
    char* ws = (char*)d_ws;

    uint16_t* t01   = (uint16_t*)(ws + OFF_T01);
    uint16_t* t02   = (uint16_t*)(ws + OFF_T02);
    uint16_t* wordb = (uint16_t*)(ws + OFF_WORD);
    uint16_t* wt    = (uint16_t*)(ws + OFF_WT);
    float*    g     = (float*)(ws + OFF_G);

    k_prep<<<J1_BLK + J2_BLK + J3_BLK, 256, 0, stream>>>(word, W1, W2, W3, tag,
                                                         T1, T2, T3, wordb, wt, g);
    k_mid<<<T01_BLK + T02_BLK, 256, 0, stream>>>(wordb, wt, g, t01, t02);
    k_final<<<NMP / 256 * (ABCP / 256), 512, 0, stream>>>(t01, t02, out);
}

// Round 5
// 100.860 us; speedup vs baseline: 1.0391x; 1.0391x over previous
//
#include <hip/hip_runtime.h>
#include <hip/hip_bf16.h>
#include <stdint.h>

#define KP    416        // padded rank (396->416) and padded wemb (400->416)
#define RANKD 396
#define WEMB  400
#define TEMB  20
#define TAGS  25
#define BATCH 16
#define LSEQ  128
#define MROWS 126        // L-2
#define NM    2016       // 16*126
#define NMP   2048
#define ABC   15625
#define ABCP  15872      // 62*256
#define SCALE 0.050251890762960605f   // 1/sqrt(396)

typedef __attribute__((ext_vector_type(8))) short short8;
typedef __attribute__((ext_vector_type(4))) float f32x4;

// workspace layout (bytes)
#define OFF_T01  0                         // 2048*416*2      = 1,703,936
#define OFF_T02  1703936                   // 15872*416*2     = 13,205,504
#define OFF_WORD 14909440                  // 16*128*416*2    = 1,703,936
#define OFF_WT   16613376                  // 3*416*416*2     = 1,038,336
#define OFF_G    17651712                  // 3*25*416*4      = 124,800

#define GLOAD_LDS16(gp, lp) \
  __builtin_amdgcn_global_load_lds((const __attribute__((address_space(1))) uint32_t*)(gp), \
                                   (__attribute__((address_space(3))) uint32_t*)(lp), 16, 0, 0)

__device__ __forceinline__ uint16_t f2bf(float f) {
    union { float f; uint32_t u; } v; v.f = f;
    uint32_t u = v.u;
    return (uint16_t)((u + 0x7FFFu + ((u >> 16) & 1u)) >> 16);  // RNE
}

// ---- prep: word->bf16 pad | W->Wt bf16 pad | g4/g5/g6 fp32 (fused by block range)
#define J1_BLK 3328   // 16*128*416/256
#define J2_BLK 2028   // 3*416*416/256
#define J3_BLK 122    // ceil(3*25*416/256)
__global__ void k_prep(const float* __restrict__ word,
                       const float* __restrict__ W1, const float* __restrict__ W2,
                       const float* __restrict__ W3, const float* __restrict__ tag,
                       const float* __restrict__ T1, const float* __restrict__ T2,
                       const float* __restrict__ T3,
                       uint16_t* __restrict__ wordb, uint16_t* __restrict__ wt,
                       float* __restrict__ g) {
    int bx = blockIdx.x;
    if (bx < J1_BLK) {
        int idx = bx * 256 + threadIdx.x;
        int e = idx % KP, row = idx / KP;
        wordb[idx] = f2bf((e < WEMB) ? word[row * WEMB + e] : 0.f);
    } else if (bx < J1_BLK + J2_BLK) {
        int idx = (bx - J1_BLK) * 256 + threadIdx.x;
        int j = idx / (KP * KP);
        int rem = idx % (KP * KP);
        int k = rem / KP, e = rem % KP;
        const float* W = (j == 0) ? W1 : (j == 1) ? W2 : W3;
        wt[idx] = f2bf((k < RANKD && e < WEMB) ? W[e * RANKD + k] : 0.f);
    } else {
        int idx = (bx - J1_BLK - J2_BLK) * 256 + threadIdx.x;
        if (idx >= 3 * TAGS * KP) return;
        int j = idx / (TAGS * KP);
        int rem = idx % (TAGS * KP);
        int a = rem / KP, k = rem % KP;
        const float* T = (j == 0) ? T1 : (j == 1) ? T2 : T3;
        float s = 0.f;
        if (k < RANKD) {
            for (int e = 0; e < TEMB; ++e) s += tag[a * TEMB + e] * T[e * RANKD + k];
        }
        g[idx] = s;
    }
}

// ---- mid: t01 build (MFMA) blocks [0,896) | t02 build blocks [896,...)
#define T01_BLK 896    // 128 nm-tiles * 7 k-groups
#define T02_BLK 3224   // 15872*52/256
__global__ __launch_bounds__(256) void k_mid(const uint16_t* __restrict__ word,
                                             const uint16_t* __restrict__ wt,
                                             const float* __restrict__ g,
                                             uint16_t* __restrict__ t01,
                                             uint16_t* __restrict__ t02) {
    int bx = blockIdx.x;
    if (bx < T01_BLK) {
        int wid = threadIdx.x >> 6, lane = threadIdx.x & 63;
        int nmtile = bx & 127;
        int ktile = (bx >> 7) * 4 + wid;
        if (ktile >= KP / 16) return;
        int col_l = lane & 15, kblk = lane >> 4;
        int colk = ktile * 16 + col_l;
        f32x4 acc1 = {0.f, 0.f, 0.f, 0.f}, acc2 = acc1, acc3 = acc1;
        if (nmtile < NM / 16) {
            int nm_a = nmtile * 16 + col_l;
            int n = nm_a / MROWS, m = nm_a % MROWS;
            const uint16_t* arow = word + (size_t)(n * LSEQ + m) * KP;
            const uint16_t* b1 = wt + (size_t)colk * KP;
            const uint16_t* b2 = wt + (size_t)KP * KP + (size_t)colk * KP;
            const uint16_t* b3 = wt + (size_t)2 * KP * KP + (size_t)colk * KP;
            for (int e0 = 0; e0 < KP; e0 += 32) {
                int eo = e0 + kblk * 8;
                short8 a0 = *(const short8*)(arow + eo);
                short8 a1 = *(const short8*)(arow + KP + eo);
                short8 a2 = *(const short8*)(arow + 2 * KP + eo);
                short8 v1 = *(const short8*)(b1 + eo);
                short8 v2 = *(const short8*)(b2 + eo);
                short8 v3 = *(const short8*)(b3 + eo);
                acc1 = __builtin_amdgcn_mfma_f32_16x16x32_bf16(a0, v1, acc1, 0, 0, 0);
                acc2 = __builtin_amdgcn_mfma_f32_16x16x32_bf16(a1, v2, acc2, 0, 0, 0);
                acc3 = __builtin_amdgcn_mfma_f32_16x16x32_bf16(a2, v3, acc3, 0, 0, 0);
            }
        }
        for (int r = 0; r < 4; ++r) {
            int row = nmtile * 16 + kblk * 4 + r;
            float v = acc1[r] * acc2[r] * acc3[r] * SCALE;
            t01[(size_t)row * KP + colk] = f2bf(v);
        }
    } else {
        int idx = (bx - T01_BLK) * 256 + threadIdx.x;
        int abc = idx / (KP / 8), kc = idx % (KP / 8);
        int k0 = kc * 8;
        short8 o;
        if (abc < ABC) {
            int a = abc / 625, rem = abc % 625, b = rem / 25, c = rem % 25;
            const float4* ga = (const float4*)(g + (size_t)a * KP + k0);
            const float4* gb = (const float4*)(g + (size_t)TAGS * KP + (size_t)b * KP + k0);
            const float4* gc = (const float4*)(g + (size_t)2 * TAGS * KP + (size_t)c * KP + k0);
            float4 a0 = ga[0], a1 = ga[1];
            float4 b0 = gb[0], b1 = gb[1];
            float4 c0 = gc[0], c1 = gc[1];
            o[0] = (short)f2bf(a0.x * b0.x * c0.x);
            o[1] = (short)f2bf(a0.y * b0.y * c0.y);
            o[2] = (short)f2bf(a0.z * b0.z * c0.z);
            o[3] = (short)f2bf(a0.w * b0.w * c0.w);
            o[4] = (short)f2bf(a1.x * b1.x * c1.x);
            o[5] = (short)f2bf(a1.y * b1.y * c1.y);
            o[6] = (short)f2bf(a1.z * b1.z * c1.z);
            o[7] = (short)f2bf(a1.w * b1.w * c1.w);
        } else {
            for (int t = 0; t < 8; ++t) o[t] = 0;
        }
        *(short8*)(t02 + (size_t)abc * KP + k0) = o;
    }
}

// ---- final: score[2016][15625] = t01 @ t02^T
// 128(M)x256(N) tile, 4 waves (wave = 128x64), depth-2 LDS dbuf, one barrier
// per K-tile (stage-late). ~240 regs -> 2 blocks/CU (cross-block overlap).
// Epilogue: LDS transpose -> float4 stores, 1 KB contiguous per wave-instr.
__global__ __launch_bounds__(256, 2) void k_final(const uint16_t* __restrict__ t01,
                                                  const uint16_t* __restrict__ t02,
                                                  float* __restrict__ out) {
    __shared__ __align__(16) char smem[49152];
    // K-loop: ldsA[2] @ [0,16KB) 8KB each; ldsB[2] @ [16KB,48KB) 16KB each.
    // epilogue: lbuf float[32][260] @ [0,33.3KB).
    float* lbuf = (float*)smem;

    const int tid = threadIdx.x;
    const int wid = tid >> 6, lane = tid & 63;
    const int col_l = lane & 15, kblk = lane >> 4;

    // XCD-aware bijective swizzle: 992 blocks = 8 x 124
    const int bid = blockIdx.x;
    const int swz = (bid & 7) * 124 + (bid >> 3);
    const int mb = swz & 15, nb = swz >> 4;   // 16 M-blocks, 62 N-blocks
    const int brow = mb * 128, bcol = nb * 256;
    const int wcol = wid * 64;

    // staging sources (k-slot-major LDS, pre-swizzled global source)
    const uint16_t* gA = t01 + (size_t)(brow + (tid & 127)) * KP + (tid >> 7) * 8;
    const uint16_t* gB = t02 + (size_t)(bcol + tid) * KP;

    f32x4 acc[8][4];
#pragma unroll
    for (int m = 0; m < 8; ++m)
#pragma unroll
        for (int n = 0; n < 4; ++n)
            acc[m][n] = (f32x4){0.f, 0.f, 0.f, 0.f};

    auto stage = [&](int buf, int kt) {
        char* ab = smem + buf * 8192 + wid * 1024;
        GLOAD_LDS16(gA + kt * 32,      ab);
        GLOAD_LDS16(gA + kt * 32 + 16, ab + 4096);
        char* bb = smem + 16384 + buf * 16384 + wid * 1024;
        GLOAD_LDS16(gB + kt * 32,      bb);
        GLOAD_LDS16(gB + kt * 32 + 8,  bb + 4096);
        GLOAD_LDS16(gB + kt * 32 + 16, bb + 8192);
        GLOAD_LDS16(gB + kt * 32 + 24, bb + 12288);
    };

    const int NT = KP / 32;   // 13
    stage(0, 0);
    stage(1, 1);
    __syncthreads();

    for (int kt = 0; kt < NT; ++kt) {
        const int cur = kt & 1;
        const uint16_t* bufA = (const uint16_t*)smem + cur * 4096;
        const uint16_t* bufB = (const uint16_t*)(smem + 16384) + cur * 8192;
        short8 aF[8], bF[4];
#pragma unroll
        for (int n = 0; n < 4; ++n)
            bF[n] = *(const short8*)(bufB + kblk * 2048 + (wcol + n * 16 + col_l) * 8);
#pragma unroll
        for (int m = 0; m < 8; ++m)
            aF[m] = *(const short8*)(bufA + kblk * 1024 + (m * 16 + col_l) * 8);
#pragma unroll
        for (int m = 0; m < 8; ++m)
#pragma unroll
            for (int n = 0; n < 4; ++n)
                acc[m][n] = __builtin_amdgcn_mfma_f32_16x16x32_bf16(aF[m], bF[n], acc[m][n], 0, 0, 0);
        if (kt + 1 < NT) {
            __syncthreads();                       // all waves done with buf[cur]
            if (kt + 2 < NT) stage(cur, kt + 2);   // refill just-vacated buffer
        }
    }

    // ---- epilogue: LDS-transposed, coalesced float4 stores ----
    __syncthreads();   // K-loop LDS reads fully done before lbuf overwrite
#pragma unroll
    for (int ch = 0; ch < 4; ++ch) {
        // scatter acc -> lbuf[32][260] (rows ch*32 .. ch*32+31 of the block)
#pragma unroll
        for (int mm = 0; mm < 2; ++mm) {
            const int m = ch * 2 + mm;
#pragma unroll
            for (int n = 0; n < 4; ++n)
#pragma unroll
                for (int r = 0; r < 4; ++r) {
                    int row_l = mm * 16 + kblk * 4 + r;
                    int col = wcol + n * 16 + col_l;
                    lbuf[row_l * 260 + col] = acc[m][n][r];
                }
        }
        __syncthreads();
        // gather rows -> contiguous float4 global stores (1 KB per wave-instr)
#pragma unroll
        for (int r8 = 0; r8 < 8; ++r8) {
            int row_l = wid * 8 + r8;
            int grow = brow + ch * 32 + row_l;
            if (grow < NM) {
                float4 v = *(const float4*)&lbuf[row_l * 260 + lane * 4];
                int gcol = bcol + lane * 4;
                float* po = out + (size_t)grow * ABC + gcol;
                if (gcol + 3 < ABC) {
                    *(float4*)po = v;
                } else {
                    if (gcol     < ABC) po[0] = v.x;
                    if (gcol + 1 < ABC) po[1] = v.y;
                    if (gcol + 2 < ABC) po[2] = v.z;
                }
            }
        }
        if (ch < 3) __syncthreads();
    }
}

extern "C" void kernel_launch(void* const* d_in, const int* in_sizes, int n_in,
                              void* d_out, int out_size, void* d_ws, size_t ws_size,
                              hipStream_t stream) {
    const float* word = (const float*)d_in[0];
    const float* tag  = (const float*)d_in[1];
    const float* W1   = (const float*)d_in[2];
    const float* W2   = (const float*)d_in[3];
    const float* W3   = (const float*)d_in[4];
    const float* T1   = (const float*)d_in[5];
    const float* T2   = (const float*)d_in[6];
    const float* T3   = (const float*)d_in[7];
    float* out = (float*)d_out;
    char* ws = (char*)d_ws;

    uint16_t* t01   = (uint16_t*)(ws + OFF_T01);
    uint16_t* t02   = (uint16_t*)(ws + OFF_T02);
    uint16_t* wordb = (uint16_t*)(ws + OFF_WORD);
    uint16_t* wt    = (uint16_t*)(ws + OFF_WT);
    float*    g     = (float*)(ws + OFF_G);

    k_prep<<<J1_BLK + J2_BLK + J3_BLK, 256, 0, stream>>>(word, W1, W2, W3, tag,
                                                         T1, T2, T3, wordb, wt, g);
    k_mid<<<T01_BLK + T02_BLK, 256, 0, stream>>>(wordb, wt, g, t01, t02);
    k_final<<<16 * 62, 256, 0, stream>>>(t01, t02, out);
}

// Round 7
// 97.171 us; speedup vs baseline: 1.0785x; 1.0380x over previous
//
#include <hip/hip_runtime.h>
#include <hip/hip_bf16.h>
#include <stdint.h>

#define KP    416        // padded rank (396->416) and padded wemb (400->416)
#define RANKD 396
#define WEMB  400
#define TEMB  20
#define TAGS  25
#define BATCH 16
#define LSEQ  128
#define MROWS 126        // L-2
#define NM    2016       // 16*126
#define NMP   2048
#define ABC   15625
#define ABCP  15872      // 62*256
#define SCALE 0.050251890762960605f   // 1/sqrt(396)

typedef __attribute__((ext_vector_type(8))) short short8;
typedef __attribute__((ext_vector_type(4))) float f32x4;

// workspace layout (bytes)
#define OFF_T01  0                         // 2048*416*2      = 1,703,936
#define OFF_T02  1703936                   // 15872*416*2     = 13,205,504
#define OFF_WORD 14909440                  // 16*128*416*2    = 1,703,936
#define OFF_WT   16613376                  // 3*416*416*2     = 1,038,336
#define OFF_G    17651712                  // 3*25*416*4      = 124,800

#define GLOAD_LDS16(gp, lp) \
  __builtin_amdgcn_global_load_lds((const __attribute__((address_space(1))) uint32_t*)(gp), \
                                   (__attribute__((address_space(3))) uint32_t*)(lp), 16, 0, 0)

__device__ __forceinline__ uint16_t f2bf(float f) {
    union { float f; uint32_t u; } v; v.f = f;
    uint32_t u = v.u;
    return (uint16_t)((u + 0x7FFFu + ((u >> 16) & 1u)) >> 16);  // RNE
}

// ---- prep: word->bf16 pad | W->Wt bf16 pad | g4/g5/g6 fp32 (fused by block range)
#define J1_BLK 3328   // 16*128*416/256
#define J2_BLK 2028   // 3*416*416/256
#define J3_BLK 122    // ceil(3*25*416/256)
__global__ void k_prep(const float* __restrict__ word,
                       const float* __restrict__ W1, const float* __restrict__ W2,
                       const float* __restrict__ W3, const float* __restrict__ tag,
                       const float* __restrict__ T1, const float* __restrict__ T2,
                       const float* __restrict__ T3,
                       uint16_t* __restrict__ wordb, uint16_t* __restrict__ wt,
                       float* __restrict__ g) {
    int bx = blockIdx.x;
    if (bx < J1_BLK) {
        int idx = bx * 256 + threadIdx.x;
        int e = idx % KP, row = idx / KP;
        wordb[idx] = f2bf((e < WEMB) ? word[row * WEMB + e] : 0.f);
    } else if (bx < J1_BLK + J2_BLK) {
        int idx = (bx - J1_BLK) * 256 + threadIdx.x;
        int j = idx / (KP * KP);
        int rem = idx % (KP * KP);
        int k = rem / KP, e = rem % KP;
        const float* W = (j == 0) ? W1 : (j == 1) ? W2 : W3;
        wt[idx] = f2bf((k < RANKD && e < WEMB) ? W[e * RANKD + k] : 0.f);
    } else {
        int idx = (bx - J1_BLK - J2_BLK) * 256 + threadIdx.x;
        if (idx >= 3 * TAGS * KP) return;
        int j = idx / (TAGS * KP);
        int rem = idx % (TAGS * KP);
        int a = rem / KP, k = rem % KP;
        const float* T = (j == 0) ? T1 : (j == 1) ? T2 : T3;
        float s = 0.f;
        if (k < RANKD) {
            for (int e = 0; e < TEMB; ++e) s += tag[a * TEMB + e] * T[e * RANKD + k];
        }
        g[idx] = s;
    }
}

// ---- mid: t01 build (MFMA) blocks [0,896) | t02 build blocks [896,...)
#define T01_BLK 896    // 128 nm-tiles * 7 k-groups
#define T02_BLK 3224   // 15872*52/256
__global__ __launch_bounds__(256) void k_mid(const uint16_t* __restrict__ word,
                                             const uint16_t* __restrict__ wt,
                                             const float* __restrict__ g,
                                             uint16_t* __restrict__ t01,
                                             uint16_t* __restrict__ t02) {
    int bx = blockIdx.x;
    if (bx < T01_BLK) {
        int wid = threadIdx.x >> 6, lane = threadIdx.x & 63;
        int nmtile = bx & 127;
        int ktile = (bx >> 7) * 4 + wid;
        if (ktile >= KP / 16) return;
        int col_l = lane & 15, kblk = lane >> 4;
        int colk = ktile * 16 + col_l;
        f32x4 acc1 = {0.f, 0.f, 0.f, 0.f}, acc2 = acc1, acc3 = acc1;
        if (nmtile < NM / 16) {
            int nm_a = nmtile * 16 + col_l;
            int n = nm_a / MROWS, m = nm_a % MROWS;
            const uint16_t* arow = word + (size_t)(n * LSEQ + m) * KP;
            const uint16_t* b1 = wt + (size_t)colk * KP;
            const uint16_t* b2 = wt + (size_t)KP * KP + (size_t)colk * KP;
            const uint16_t* b3 = wt + (size_t)2 * KP * KP + (size_t)colk * KP;
            for (int e0 = 0; e0 < KP; e0 += 32) {
                int eo = e0 + kblk * 8;
                short8 a0 = *(const short8*)(arow + eo);
                short8 a1 = *(const short8*)(arow + KP + eo);
                short8 a2 = *(const short8*)(arow + 2 * KP + eo);
                short8 v1 = *(const short8*)(b1 + eo);
                short8 v2 = *(const short8*)(b2 + eo);
                short8 v3 = *(const short8*)(b3 + eo);
                acc1 = __builtin_amdgcn_mfma_f32_16x16x32_bf16(a0, v1, acc1, 0, 0, 0);
                acc2 = __builtin_amdgcn_mfma_f32_16x16x32_bf16(a1, v2, acc2, 0, 0, 0);
                acc3 = __builtin_amdgcn_mfma_f32_16x16x32_bf16(a2, v3, acc3, 0, 0, 0);
            }
        }
        for (int r = 0; r < 4; ++r) {
            int row = nmtile * 16 + kblk * 4 + r;
            float v = acc1[r] * acc2[r] * acc3[r] * SCALE;
            t01[(size_t)row * KP + colk] = f2bf(v);
        }
    } else {
        int idx = (bx - T01_BLK) * 256 + threadIdx.x;
        int abc = idx / (KP / 8), kc = idx % (KP / 8);
        int k0 = kc * 8;
        short8 o;
        if (abc < ABC) {
            int a = abc / 625, rem = abc % 625, b = rem / 25, c = rem % 25;
            const float4* ga = (const float4*)(g + (size_t)a * KP + k0);
            const float4* gb = (const float4*)(g + (size_t)TAGS * KP + (size_t)b * KP + k0);
            const float4* gc = (const float4*)(g + (size_t)2 * TAGS * KP + (size_t)c * KP + k0);
            float4 a0 = ga[0], a1 = ga[1];
            float4 b0 = gb[0], b1 = gb[1];
            float4 c0 = gc[0], c1 = gc[1];
            o[0] = (short)f2bf(a0.x * b0.x * c0.x);
            o[1] = (short)f2bf(a0.y * b0.y * c0.y);
            o[2] = (short)f2bf(a0.z * b0.z * c0.z);
            o[3] = (short)f2bf(a0.w * b0.w * c0.w);
            o[4] = (short)f2bf(a1.x * b1.x * c1.x);
            o[5] = (short)f2bf(a1.y * b1.y * c1.y);
            o[6] = (short)f2bf(a1.z * b1.z * c1.z);
            o[7] = (short)f2bf(a1.w * b1.w * c1.w);
        } else {
            for (int t = 0; t < 8; ++t) o[t] = 0;
        }
        *(short8*)(t02 + (size_t)abc * KP + k0) = o;
    }
}

// ---- final: score[2016][15625] = t01 @ t02^T
// 128(M)x256(N) tile, 4 waves (wave = 128x64), depth-2 LDS dbuf, one barrier
// per K-tile (stage-late). Epilogue: LDS transpose -> NON-TEMPORAL f32x4
// stores (bypass L2 so the 126 MB write stream doesn't evict t01/t02).
__global__ __launch_bounds__(256, 2) void k_final(const uint16_t* __restrict__ t01,
                                                  const uint16_t* __restrict__ t02,
                                                  float* __restrict__ out) {
    __shared__ __align__(16) char smem[49152];
    // K-loop: ldsA[2] @ [0,16KB) 8KB each; ldsB[2] @ [16KB,48KB) 16KB each.
    // epilogue: lbuf float[32][260] @ [0,33.3KB).
    float* lbuf = (float*)smem;

    const int tid = threadIdx.x;
    const int wid = tid >> 6, lane = tid & 63;
    const int col_l = lane & 15, kblk = lane >> 4;

    // XCD-aware bijective swizzle: 992 blocks = 8 x 124
    const int bid = blockIdx.x;
    const int swz = (bid & 7) * 124 + (bid >> 3);
    const int mb = swz & 15, nb = swz >> 4;   // 16 M-blocks, 62 N-blocks
    const int brow = mb * 128, bcol = nb * 256;
    const int wcol = wid * 64;

    // staging sources (k-slot-major LDS, pre-swizzled global source)
    const uint16_t* gA = t01 + (size_t)(brow + (tid & 127)) * KP + (tid >> 7) * 8;
    const uint16_t* gB = t02 + (size_t)(bcol + tid) * KP;

    f32x4 acc[8][4];
#pragma unroll
    for (int m = 0; m < 8; ++m)
#pragma unroll
        for (int n = 0; n < 4; ++n)
            acc[m][n] = (f32x4){0.f, 0.f, 0.f, 0.f};

    auto stage = [&](int buf, int kt) {
        char* ab = smem + buf * 8192 + wid * 1024;
        GLOAD_LDS16(gA + kt * 32,      ab);
        GLOAD_LDS16(gA + kt * 32 + 16, ab + 4096);
        char* bb = smem + 16384 + buf * 16384 + wid * 1024;
        GLOAD_LDS16(gB + kt * 32,      bb);
        GLOAD_LDS16(gB + kt * 32 + 8,  bb + 4096);
        GLOAD_LDS16(gB + kt * 32 + 16, bb + 8192);
        GLOAD_LDS16(gB + kt * 32 + 24, bb + 12288);
    };

    const int NT = KP / 32;   // 13
    stage(0, 0);
    stage(1, 1);
    __syncthreads();

    for (int kt = 0; kt < NT; ++kt) {
        const int cur = kt & 1;
        const uint16_t* bufA = (const uint16_t*)smem + cur * 4096;
        const uint16_t* bufB = (const uint16_t*)(smem + 16384) + cur * 8192;
        short8 aF[8], bF[4];
#pragma unroll
        for (int n = 0; n < 4; ++n)
            bF[n] = *(const short8*)(bufB + kblk * 2048 + (wcol + n * 16 + col_l) * 8);
#pragma unroll
        for (int m = 0; m < 8; ++m)
            aF[m] = *(const short8*)(bufA + kblk * 1024 + (m * 16 + col_l) * 8);
#pragma unroll
        for (int m = 0; m < 8; ++m)
#pragma unroll
            for (int n = 0; n < 4; ++n)
                acc[m][n] = __builtin_amdgcn_mfma_f32_16x16x32_bf16(aF[m], bF[n], acc[m][n], 0, 0, 0);
        if (kt + 1 < NT) {
            __syncthreads();                       // all waves done with buf[cur]
            if (kt + 2 < NT) stage(cur, kt + 2);   // refill just-vacated buffer
        }
    }

    // ---- epilogue: LDS-transposed, coalesced NON-TEMPORAL f32x4 stores ----
    __syncthreads();   // K-loop LDS reads fully done before lbuf overwrite
#pragma unroll
    for (int ch = 0; ch < 4; ++ch) {
        // scatter acc -> lbuf[32][260] (rows ch*32 .. ch*32+31 of the block)
#pragma unroll
        for (int mm = 0; mm < 2; ++mm) {
            const int m = ch * 2 + mm;
#pragma unroll
            for (int n = 0; n < 4; ++n)
#pragma unroll
                for (int r = 0; r < 4; ++r) {
                    int row_l = mm * 16 + kblk * 4 + r;
                    int col = wcol + n * 16 + col_l;
                    lbuf[row_l * 260 + col] = acc[m][n][r];
                }
        }
        __syncthreads();
        // gather rows -> contiguous f32x4 nt stores (1 KB per wave-instr)
#pragma unroll
        for (int r8 = 0; r8 < 8; ++r8) {
            int row_l = wid * 8 + r8;
            int grow = brow + ch * 32 + row_l;
            if (grow < NM) {
                f32x4 v = *(const f32x4*)&lbuf[row_l * 260 + lane * 4];
                int gcol = bcol + lane * 4;
                float* po = out + (size_t)grow * ABC + gcol;
                if (gcol + 3 < ABC) {
                    __builtin_nontemporal_store(v, (f32x4*)po);
                } else {
                    if (gcol     < ABC) po[0] = v[0];
                    if (gcol + 1 < ABC) po[1] = v[1];
                    if (gcol + 2 < ABC) po[2] = v[2];
                }
            }
        }
        if (ch < 3) __syncthreads();
    }
}

extern "C" void kernel_launch(void* const* d_in, const int* in_sizes, int n_in,
                              void* d_out, int out_size, void* d_ws, size_t ws_size,
                              hipStream_t stream) {
    const float* word = (const float*)d_in[0];
    const float* tag  = (const float*)d_in[1];
    const float* W1   = (const float*)d_in[2];
    const float* W2   = (const float*)d_in[3];
    const float* W3   = (const float*)d_in[4];
    const float* T1   = (const float*)d_in[5];
    const float* T2   = (const float*)d_in[6];
    const float* T3   = (const float*)d_in[7];
    float* out = (float*)d_out;
    char* ws = (char*)d_ws;

    uint16_t* t01   = (uint16_t*)(ws + OFF_T01);
    uint16_t* t02   = (uint16_t*)(ws + OFF_T02);
    uint16_t* wordb = (uint16_t*)(ws + OFF_WORD);
    uint16_t* wt    = (uint16_t*)(ws + OFF_WT);
    float*    g     = (float*)(ws + OFF_G);

    k_prep<<<J1_BLK + J2_BLK + J3_BLK, 256, 0, stream>>>(word, W1, W2, W3, tag,
                                                         T1, T2, T3, wordb, wt, g);
    k_mid<<<T01_BLK + T02_BLK, 256, 0, stream>>>(wordb, wt, g, t01, t02);
    k_final<<<16 * 62, 256, 0, stream>>>(t01, t02, out);
}